// Round 1
// 8301.512 us; speedup vs baseline: 1.7476x; 1.7476x over previous
//
#include <hip/hip_runtime.h>
#include <math.h>

#define BB 4
#define TT 512
#define DD 768
#define NH 12
#define HDIM 64
#define NL 12
#define DFF 2048
#define NVOCAB 50257
#define NMEM 1024
#define KTOP 8
#define NLAT 4
#define CAPK 64
#define NTOK (BB*TT)        // 2048
#define NTOKD ((long)NTOK*DD) // 1572864

typedef __attribute__((ext_vector_type(8))) short bf16x8;
typedef __attribute__((ext_vector_type(4))) float f32x4;

// ---------------------------------------------------------------------------
// Split-bf16 (bf16x3) MFMA GEMM: C[m,n] = epi( scale * sum_k A[m,k]*W[n,k] )
// fp32 operands are split in-kernel into hi/lo bf16 (v ~= hi + lo, RNE);
// A.W^T computed as Ahi.Whi + Ahi.Wlo + Alo.Whi on the matrix pipe with
// fp32 accumulation -> relative error ~2^-16 (fp32-class, safe for the
// discrete top-k routing), at ~833 TF effective ceiling vs 157 TF fp32 VALU.
// A: [M,K] row stride lda. W: [N,K] row stride ldb.  Batched via blockIdx.z.
// EPI 0: C = v*scale
// EPI 1: C = aux[m*ldc+n] + v        (residual add)
// EPI 2: C = gelu_exact(v + aux[n])  (bias + exact GELU)
// EPI 3: C = (n>m) ? -inf : v*scale  (causal mask)
// M must be a multiple of 128; N bounds-checked; K multiple of 32.
// Tile 128x128, BK=32, 4 waves (2x2), 64x64 per wave, 16x16x32 bf16 MFMA.
// MFMA operand/result maps (m89-verified family layout):
//   A-frag: lane l holds A[row=l&15][k=8*(l>>4)+i]  (k-perm cancels A vs B)
//   B-frag: lane l holds W[col=l&15][k=8*(l>>4)+i]
//   D:      lane l reg r -> row=(l>>4)*4+r, col=l&15
// ---------------------------------------------------------------------------

__device__ __forceinline__ unsigned bf16rne(float v) {
    unsigned u = __builtin_bit_cast(unsigned, v);
    return u + 0x7fffu + ((u >> 16) & 1u);   // top 16 bits = RNE bf16
}

__device__ __forceinline__ void split4(const float4 v, uint2& hi, uint2& lo) {
    unsigned rx = bf16rne(v.x), ry = bf16rne(v.y);
    unsigned rz = bf16rne(v.z), rw_ = bf16rne(v.w);
    hi.x = (rx >> 16) | (ry & 0xffff0000u);
    hi.y = (rz >> 16) | (rw_ & 0xffff0000u);
    float dx = v.x - __builtin_bit_cast(float, rx & 0xffff0000u);
    float dy = v.y - __builtin_bit_cast(float, ry & 0xffff0000u);
    float dz = v.z - __builtin_bit_cast(float, rz & 0xffff0000u);
    float dw = v.w - __builtin_bit_cast(float, rw_ & 0xffff0000u);
    unsigned lx = bf16rne(dx), ly = bf16rne(dy);
    unsigned lz = bf16rne(dz), lw = bf16rne(dw);
    lo.x = (lx >> 16) | (ly & 0xffff0000u);
    lo.y = (lz >> 16) | (lw & 0xffff0000u);
}

template<int EPI>
__global__ __launch_bounds__(256, 2)
void gemm_nt(const float* __restrict__ A, const float* __restrict__ W,
             float* __restrict__ C, const float* __restrict__ aux,
             int M, int N, int K, int lda, int ldb, int ldc, float scale,
             int zdiv, long sAb, long sAh, long sBb, long sBh, long sCb, long sCh)
{
    // 40-ushort row stride (80B): 16B-aligned b128 reads, <=2-way bank alias (free)
    __shared__ unsigned short As_hi[128][40];
    __shared__ unsigned short As_lo[128][40];
    __shared__ unsigned short Ws_hi[128][40];
    __shared__ unsigned short Ws_lo[128][40];

    const int z  = blockIdx.z;
    const int bz = z / zdiv, hz = z % zdiv;
    A += (long)bz*sAb + (long)hz*sAh;
    W += (long)bz*sBb + (long)hz*sBh;
    C += (long)bz*sCb + (long)hz*sCh;

    const int row0 = blockIdx.y * 128, col0 = blockIdx.x * 128;
    const int tid  = threadIdx.x;
    // staging map: 4 iters j, linear li = tid + j*256 -> row = srow+j*32, col = sc4
    const int srow = tid >> 3;           // 0..31
    const int sc4  = (tid & 7) << 2;     // 0,4,...,28
    // wave decomposition: 2x2 waves, 64x64 per wave
    const int wid = tid >> 6, lane = tid & 63;
    const int wm = (wid >> 1) << 6, wn = (wid & 1) << 6;
    const int lr = lane & 15, lg = lane >> 4;

    f32x4 acc[4][4] = {};   // acc[mi][ni]

    const float* Abase = A + (long)row0 * lda + sc4;
    const float* Wbase = W + (long)col0 * ldb + sc4;

    float4 ra[4], rw[4];
    auto loadk = [&](int kk) {
        #pragma unroll
        for (int j = 0; j < 4; ++j) {
            const int r = srow + (j << 5);
            ra[j] = *(const float4*)(Abase + (long)r * lda + kk);
            const int wr = col0 + r;
            if (wr < N) rw[j] = *(const float4*)(Wbase + (long)r * ldb + kk);
            else        rw[j] = make_float4(0.f, 0.f, 0.f, 0.f);
        }
    };
    loadk(0);

    for (int kk = 0; kk < K; kk += 32) {
        // convert staged registers -> hi/lo bf16 in LDS
        #pragma unroll
        for (int j = 0; j < 4; ++j) {
            const int r = srow + (j << 5);
            uint2 h, l;
            split4(ra[j], h, l);
            *(uint2*)&As_hi[r][sc4] = h;
            *(uint2*)&As_lo[r][sc4] = l;
            split4(rw[j], h, l);
            *(uint2*)&Ws_hi[r][sc4] = h;
            *(uint2*)&Ws_lo[r][sc4] = l;
        }
        __syncthreads();
        if (kk + 32 < K) loadk(kk + 32);   // prefetch next slab under MFMA phase

        bf16x8 ah[4], al[4], bh[4], bl[4];
        #pragma unroll
        for (int i = 0; i < 4; ++i) {
            ah[i] = *(const bf16x8*)&As_hi[wm + (i << 4) + lr][lg << 3];
            al[i] = *(const bf16x8*)&As_lo[wm + (i << 4) + lr][lg << 3];
            bh[i] = *(const bf16x8*)&Ws_hi[wn + (i << 4) + lr][lg << 3];
            bl[i] = *(const bf16x8*)&Ws_lo[wn + (i << 4) + lr][lg << 3];
        }
        #pragma unroll
        for (int i = 0; i < 4; ++i)
            #pragma unroll
            for (int j = 0; j < 4; ++j) {
                acc[i][j] = __builtin_amdgcn_mfma_f32_16x16x32_bf16(ah[i], bh[j], acc[i][j], 0, 0, 0);
                acc[i][j] = __builtin_amdgcn_mfma_f32_16x16x32_bf16(ah[i], bl[j], acc[i][j], 0, 0, 0);
                acc[i][j] = __builtin_amdgcn_mfma_f32_16x16x32_bf16(al[i], bh[j], acc[i][j], 0, 0, 0);
            }
        __syncthreads();
    }

    // epilogue: D lane l reg r -> row=(l>>4)*4+r, col=l&15
    #pragma unroll
    for (int i = 0; i < 4; ++i) {
        #pragma unroll
        for (int j = 0; j < 4; ++j) {
            #pragma unroll
            for (int r = 0; r < 4; ++r) {
                const int m = row0 + wm + (i << 4) + (lg << 2) + r;
                const int n = col0 + wn + (j << 4) + lr;
                if (n >= N) continue;
                float v = acc[i][j][r];
                long idx = (long)m * ldc + n;
                if (EPI == 0)      C[idx] = v * scale;
                else if (EPI == 1) C[idx] = aux[idx] + v;
                else if (EPI == 2) { float u = v + aux[n];
                                     C[idx] = 0.5f*u*(1.f + erff(u*0.70710678118654752f)); }
                else               C[idx] = (n > m) ? -INFINITY : v * scale;
            }
        }
    }
}

// ---------------- softmax over score row + A@V, one wave per (b,h,q) --------
__global__ __launch_bounds__(64)
void softmax_av_k(const float* __restrict__ scores, const float* __restrict__ qkv,
                  float* __restrict__ attno)
{
    const int q = blockIdx.x, h = blockIdx.y, b = blockIdx.z;
    const int lane = threadIdx.x;
    const float* srow = scores + ((long)(b*NH + h)*TT + q)*TT;
    __shared__ float p[TT];
    float loc[TT/64];
    float mx = -INFINITY;
    #pragma unroll
    for (int i=0;i<TT/64;i++){ loc[i] = srow[lane + (i<<6)]; mx = fmaxf(mx, loc[i]); }
    #pragma unroll
    for (int o=32;o;o>>=1) mx = fmaxf(mx, __shfl_xor(mx, o));
    float sum = 0.f;
    #pragma unroll
    for (int i=0;i<TT/64;i++){ loc[i] = expf(loc[i]-mx); sum += loc[i]; }
    #pragma unroll
    for (int o=32;o;o>>=1) sum += __shfl_xor(sum, o);
    const float inv = 1.f/sum;
    #pragma unroll
    for (int i=0;i<TT/64;i++) p[lane + (i<<6)] = loc[i]*inv;
    __syncthreads();
    const float* vbase = qkv + (long)b*TT*3*DD + 2*DD + h*HDIM + lane;
    float acc = 0.f;
    #pragma unroll 4
    for (int k=0;k<=q;k++) acc = fmaf(p[k], vbase[(long)k*3*DD], acc);
    attno[((long)b*TT + q)*DD + h*HDIM + lane] = acc;
}

// ---------------- RMSNorm, one block per row --------------------------------
__global__ __launch_bounds__(256)
void rmsnorm_k(const float* __restrict__ x, const float* __restrict__ w,
               float* __restrict__ y)
{
    const int row = blockIdx.x, tid = threadIdx.x;
    const float* xr = x + (long)row*DD;
    float s = 0.f;
    for (int j=tid;j<DD;j+=256){ float v = xr[j]; s = fmaf(v,v,s); }
    __shared__ float red[256];
    red[tid] = s; __syncthreads();
    for (int o=128;o;o>>=1){ if (tid<o) red[tid]+=red[tid+o]; __syncthreads(); }
    const float inv = rsqrtf(red[0]*(1.f/DD) + 1e-6f);
    for (int j=tid;j<DD;j+=256) y[(long)row*DD + j] = xr[j]*inv*w[j];
}

// ---------------- router score: dot(x_row, rw) ------------------------------
__global__ __launch_bounds__(256)
void router_k(const float* __restrict__ x, const float* __restrict__ rw,
              float* __restrict__ sc)
{
    const int row = blockIdx.x, tid = threadIdx.x;
    const float* xr = x + (long)row*DD;
    float s = 0.f;
    for (int j=tid;j<DD;j+=256) s = fmaf(xr[j], rw[j], s);
    __shared__ float red[256];
    red[tid] = s; __syncthreads();
    for (int o=128;o;o>>=1){ if (tid<o) red[tid]+=red[tid+o]; __syncthreads(); }
    if (tid==0) sc[row] = red[0];
}

// ---------------- exact top-64 mask per batch row (jax tie: lower idx) ------
__global__ __launch_bounds__(512)
void topk_mask_k(const float* __restrict__ sc, int* __restrict__ sel)
{
    const int b = blockIdx.x, t = threadIdx.x;
    __shared__ float v[TT]; __shared__ float rv[TT]; __shared__ int ri[TT];
    v[t] = sc[b*TT + t];
    sel[b*TT + t] = 0;
    __syncthreads();
    for (int it=0; it<CAPK; ++it){
        rv[t] = v[t]; ri[t] = t; __syncthreads();
        for (int o=256;o;o>>=1){
            if (t<o){
                if (rv[t+o] > rv[t] || (rv[t+o]==rv[t] && ri[t+o] < ri[t])){
                    rv[t]=rv[t+o]; ri[t]=ri[t+o];
                }
            }
            __syncthreads();
        }
        if (t==0){ sel[b*TT + ri[0]] = 1; v[ri[0]] = -INFINITY; }
        __syncthreads();
    }
}

__global__ void select_k(float* __restrict__ x, const float* __restrict__ xn,
                         const int* __restrict__ sel)
{
    const long i = (long)blockIdx.x*256 + threadIdx.x;
    if (sel[i/DD]) x[i] = xn[i];
}

__global__ void swiglu_k(float* __restrict__ h1, const float* __restrict__ h2)
{
    const long i = (long)blockIdx.x*256 + threadIdx.x;
    float a = h1[i];
    h1[i] = (a/(1.f+expf(-a))) * h2[i];
}

// ---------------- kNN: top-8 of 1024 sims, softmax, gather ------------------
__global__ __launch_bounds__(64)
void knn_k(const float* __restrict__ sim, const float* __restrict__ mv,
           float* __restrict__ rpre)
{
    const int row = blockIdx.x, lane = threadIdx.x;
    __shared__ float sl[NMEM];
    for (int i=lane;i<NMEM;i+=64) sl[i] = sim[(long)row*NMEM + i];
    __syncthreads();
    float val8[KTOP]; int idx8[KTOP];
    for (int j=0;j<KTOP;j++){
        float bv = -INFINITY; int bi = NMEM;
        for (int i=lane;i<NMEM;i+=64){
            float vv = sl[i];
            if (vv > bv || (vv==bv && i < bi)){ bv=vv; bi=i; }
        }
        #pragma unroll
        for (int o=32;o;o>>=1){
            float ov = __shfl_xor(bv,o); int oi = __shfl_xor(bi,o);
            if (ov > bv || (ov==bv && oi < bi)){ bv=ov; bi=oi; }
        }
        val8[j]=bv; idx8[j]=bi;
        if (lane==0) sl[bi] = -INFINITY;
        __syncthreads();
    }
    const float mx = val8[0];
    float w8[KTOP]; float ssum = 0.f;
    #pragma unroll
    for (int j=0;j<KTOP;j++){ w8[j] = expf(val8[j]-mx); ssum += w8[j]; }
    const float inv = 1.f/ssum;
    for (int c=0;c<DD/64;c++){
        const int d = lane + (c<<6);
        float acc = 0.f;
        #pragma unroll
        for (int j=0;j<KTOP;j++) acc = fmaf(w8[j], mv[(long)idx8[j]*DD + d], acc);
        rpre[(long)row*DD + d] = acc*inv;
    }
}

__global__ void concat_k(const float* __restrict__ x, const float* __restrict__ r,
                         float* __restrict__ gi)
{
    const long i = (long)blockIdx.x*256 + threadIdx.x;
    const long row = i / (2*DD); const int c = (int)(i % (2*DD));
    gi[i] = (c < DD) ? x[row*DD + c] : r[row*DD + c - DD];
}

// ---------------- gate scalar: sigmoid(dot(g1,w2)+b2), wave per row ---------
__global__ __launch_bounds__(256)
void gate2_k(const float* __restrict__ g1, const float* __restrict__ w2,
             const float* __restrict__ b2, float* __restrict__ gate)
{
    const int row  = blockIdx.x*4 + (threadIdx.x >> 6);
    const int lane = threadIdx.x & 63;
    const float* gr = g1 + (long)row*(DD/2);
    float s = 0.f;
    for (int j=lane;j<DD/2;j+=64) s = fmaf(gr[j], w2[j], s);
    #pragma unroll
    for (int o=32;o;o>>=1) s += __shfl_xor(s,o);
    if (lane==0) gate[row] = 1.f/(1.f+expf(-(s + b2[0])));
}

__global__ void gateadd_k(float* __restrict__ x, const float* __restrict__ r,
                          const float* __restrict__ gate)
{
    const long i = (long)blockIdx.x*256 + threadIdx.x;
    x[i] += gate[i/DD]*r[i];
}

__global__ void embed_k(const int* __restrict__ ids, const float* __restrict__ ew,
                        const float* __restrict__ pw, float* __restrict__ x)
{
    const long i = (long)blockIdx.x*256 + threadIdx.x;
    const long row = i / DD; const int d = (int)(i % DD); const int t = (int)(row % TT);
    x[i] = ew[(long)ids[row]*DD + d] + pw[(long)t*DD + d];
}

// ---------------------------------------------------------------------------
static void launch_gemm(hipStream_t s, int epi, const float* A, const float* W,
                        float* C, const float* aux, int M, int N, int K,
                        int lda, int ldb, int ldc, float scale,
                        int nz=1, int zdiv=1, long sAb=0, long sAh=0,
                        long sBb=0, long sBh=0, long sCb=0, long sCh=0)
{
    dim3 g((N+127)/128, M/128, nz), blk(256,1,1);
    switch (epi){
    case 0: gemm_nt<0><<<g,blk,0,s>>>(A,W,C,aux,M,N,K,lda,ldb,ldc,scale,zdiv,sAb,sAh,sBb,sBh,sCb,sCh); break;
    case 1: gemm_nt<1><<<g,blk,0,s>>>(A,W,C,aux,M,N,K,lda,ldb,ldc,scale,zdiv,sAb,sAh,sBb,sBh,sCb,sCh); break;
    case 2: gemm_nt<2><<<g,blk,0,s>>>(A,W,C,aux,M,N,K,lda,ldb,ldc,scale,zdiv,sAb,sAh,sBb,sBh,sCb,sCh); break;
    default:gemm_nt<3><<<g,blk,0,s>>>(A,W,C,aux,M,N,K,lda,ldb,ldc,scale,zdiv,sAb,sAh,sBb,sBh,sCb,sCh); break;
    }
}

struct Bufs { float *x2, *xnew, *hn, *attno, *qkv, *big; };

static void run_tblock(hipStream_t s, const float* qw, const float* ow,
                       const float* n1, const float* n2, const float* w1,
                       const float* w2, const float* w3,
                       const float* xin, float* xout, const Bufs& bf)
{
    // attention
    rmsnorm_k<<<NTOK,256,0,s>>>(xin, n1, bf.hn);
    launch_gemm(s, 0, bf.hn, qw, bf.qkv, nullptr, NTOK, 3*DD, DD, DD, DD, 3*DD, 1.f);
    float* scores = bf.big;   // [B,H,T,T]
    launch_gemm(s, 3, bf.qkv, bf.qkv + DD, scores, nullptr, TT, TT, HDIM,
                3*DD, 3*DD, TT, 0.125f,
                BB*NH, NH,
                (long)TT*3*DD, HDIM,          // A (Q) strides per b, per h
                (long)TT*3*DD, HDIM,          // W (K) strides
                (long)NH*TT*TT, (long)TT*TT); // C strides
    softmax_av_k<<<dim3(TT,NH,BB),64,0,s>>>(scores, bf.qkv, bf.attno);
    launch_gemm(s, 1, bf.attno, ow, bf.x2, xin, NTOK, DD, DD, DD, DD, DD, 1.f);
    // FFN (SwiGLU)
    rmsnorm_k<<<NTOK,256,0,s>>>(bf.x2, n2, bf.hn);
    float* h1 = bf.big; float* h2 = bf.big + (long)NTOK*DFF;
    launch_gemm(s, 0, bf.hn, w1, h1, nullptr, NTOK, DFF, DD, DD, DD, DFF, 1.f);
    launch_gemm(s, 0, bf.hn, w2, h2, nullptr, NTOK, DFF, DD, DD, DD, DFF, 1.f);
    swiglu_k<<<(NTOK*DFF)/256,256,0,s>>>(h1, h2);
    launch_gemm(s, 1, h1, w3, xout, bf.x2, NTOK, DD, DFF, DFF, DFF, DD, 1.f);
}

extern "C" void kernel_launch(void* const* d_in, const int* in_sizes, int n_in,
                              void* d_out, int out_size, void* d_ws, size_t ws_size,
                              hipStream_t stream)
{
    const int*   ids        = (const int*)  d_in[0];
    const float* embed_w    = (const float*)d_in[1];
    const float* pos_w      = (const float*)d_in[2];
    const float* qkv_w      = (const float*)d_in[3];
    const float* out_w      = (const float*)d_in[4];
    const float* norm1_w    = (const float*)d_in[5];
    const float* norm2_w    = (const float*)d_in[6];
    const float* ff_w1      = (const float*)d_in[7];
    const float* ff_w2      = (const float*)d_in[8];
    const float* ff_w3      = (const float*)d_in[9];
    const float* router_w   = (const float*)d_in[10];
    const float* lat_qkv_w  = (const float*)d_in[11];
    const float* lat_out_w  = (const float*)d_in[12];
    const float* lat_n1     = (const float*)d_in[13];
    const float* lat_n2     = (const float*)d_in[14];
    const float* lat_w1     = (const float*)d_in[15];
    const float* lat_w2     = (const float*)d_in[16];
    const float* lat_w3     = (const float*)d_in[17];
    const float* mem_keys   = (const float*)d_in[18];
    const float* mem_values = (const float*)d_in[19];
    const float* mem_qp     = (const float*)d_in[20];
    const float* mem_op     = (const float*)d_in[21];
    const float* gate_w1    = (const float*)d_in[22];
    const float* gate_b1    = (const float*)d_in[23];
    const float* gate_w2    = (const float*)d_in[24];
    const float* gate_b2    = (const float*)d_in[25];
    const float* fnorm_w    = (const float*)d_in[26];
    float* out = (float*)d_out;

    // workspace layout (floats) — ~100.7 MB total
    float* ws = (float*)d_ws;
    float* x     = ws;                      // 1.57M
    Bufs bf;
    bf.x2    = x        + NTOKD;            // 1.57M
    bf.xnew  = bf.x2    + NTOKD;            // 1.57M
    bf.hn    = bf.xnew  + NTOKD;            // 1.57M
    bf.attno = bf.hn    + NTOKD;            // 1.57M
    bf.qkv   = bf.attno + NTOKD;            // 4.72M  (also qmem/rpre/retr later)
    bf.big   = bf.qkv   + 3*NTOKD;          // 12.58M (scores | h1+h2 | sim+gi+g1)
    float* rsc   = bf.big + (long)BB*NH*TT*TT;
    float* gateb = rsc + NTOK;
    int*   sel   = (int*)(gateb + NTOK);

    embed_k<<<(int)(NTOKD/256),256,0,stream>>>(ids, embed_w, pos_w, x);

    for (int i=0;i<NL;i++){
        const float* qw = qkv_w + (long)i*3*DD*DD;
        const float* ow = out_w + (long)i*DD*DD;
        const float* n1 = norm1_w + (long)i*DD;
        const float* n2 = norm2_w + (long)i*DD;
        const float* w1 = ff_w1 + (long)i*DFF*DD;
        const float* w2 = ff_w2 + (long)i*DFF*DD;
        const float* w3 = ff_w3 + (long)i*DD*DFF;
        if (i & 1){  // MoD layer: full block, then select top-64 tokens per batch
            router_k<<<NTOK,256,0,stream>>>(x, router_w + (long)i*DD, rsc);
            topk_mask_k<<<BB,TT,0,stream>>>(rsc, sel);
            run_tblock(stream, qw,ow,n1,n2,w1,w2,w3, x, bf.xnew, bf);
            select_k<<<(int)(NTOKD/256),256,0,stream>>>(x, bf.xnew, sel);
        } else {
            run_tblock(stream, qw,ow,n1,n2,w1,w2,w3, x, x, bf);
        }
    }
    for (int r=0;r<NLAT;r++)
        run_tblock(stream, lat_qkv_w, lat_out_w, lat_n1, lat_n2,
                   lat_w1, lat_w2, lat_w3, x, x, bf);

    // kNN memory retrieval
    float* qmem = bf.qkv;
    float* rpre = bf.qkv + NTOKD;
    float* retr = bf.qkv + 2*NTOKD;
    launch_gemm(stream, 0, x, mem_qp, qmem, nullptr, NTOK, DD, DD, DD, DD, DD, 1.f);
    float* sim = bf.big;
    launch_gemm(stream, 0, qmem, mem_keys, sim, nullptr, NTOK, NMEM, DD, DD, DD, NMEM,
                0.036084391824351615f /* 1/sqrt(768) */);
    knn_k<<<NTOK,64,0,stream>>>(sim, mem_values, rpre);
    launch_gemm(stream, 0, rpre, mem_op, retr, nullptr, NTOK, DD, DD, DD, DD, DD, 1.f);

    // gated fusion
    float* gi = bf.big + (long)NTOK*NMEM;
    concat_k<<<(int)((long)NTOK*2*DD/256),256,0,stream>>>(x, retr, gi);
    float* g1 = gi + (long)NTOK*2*DD;
    launch_gemm(stream, 2, gi, gate_w1, g1, gate_b1, NTOK, DD/2, 2*DD, 2*DD, 2*DD, DD/2, 1.f);
    gate2_k<<<NTOK/4,256,0,stream>>>(g1, gate_w2, gate_b2, gateb);
    gateadd_k<<<(int)(NTOKD/256),256,0,stream>>>(x, retr, gateb);

    // final norm + tied lm_head
    rmsnorm_k<<<NTOK,256,0,stream>>>(x, fnorm_w, bf.hn);
    launch_gemm(stream, 0, bf.hn, embed_w, out, nullptr, NTOK, NVOCAB, DD, DD, DD, NVOCAB, 1.f);
}